// Round 1
// baseline (188.116 us; speedup 1.0000x reference)
//
#include <hip/hip_runtime.h>

#define EPS 1e-3f
#define NPIX  50176   // 16*56*56
#define NOPIX 12544   // 16*28*28

// ws float offsets
#define OFF_T1W  0        // [32 g][16 ch][8 t' + 32 w'] = 20480 (w' = s1*W1, t' = t1/s1)
#define OFF_S2   20480    // [32][4]
#define OFF_T2   20608    // [32][4]
#define OFF_T3   20736    // [128]
#define OFF_BSUM 20864    // [256]
#define OFF_W3S  21120    // [9 kk][4 ci][32 g][4 f] pre-scaled by s3
#define OFF_U    25728    // [32 g][50176 px] ushort4 (bf16, g-planar)

__device__ __forceinline__ unsigned short f2bf(float f) {
    unsigned u = __float_as_uint(f);
    return (unsigned short)((u + 0x7fffu + ((u >> 16) & 1u)) >> 16);
}
__device__ __forceinline__ float bf2f(unsigned short s) {
    return __uint_as_float(((unsigned)s) << 16);
}

__global__ __launch_bounds__(256)
void prep_kernel(const float* __restrict__ g1, const float* __restrict__ be1,
                 const float* __restrict__ m1, const float* __restrict__ v1,
                 const float* __restrict__ W1, const float* __restrict__ b1,
                 const float* __restrict__ g2, const float* __restrict__ be2,
                 const float* __restrict__ m2, const float* __restrict__ v2,
                 const float* __restrict__ W3, const float* __restrict__ b3,
                 const float* __restrict__ g3, const float* __restrict__ be3,
                 const float* __restrict__ m3, const float* __restrict__ v3,
                 const float* __restrict__ b2, float* __restrict__ ws) {
    int gid = blockIdx.x * 256 + threadIdx.x;
    int stride = gridDim.x * 256;
    // T1W: per (g,c): t' = t1/s1 and w'_f = s1*W1[c][f]   (s1 > 0 always)
    for (int i = gid; i < 4096; i += stride) {
        int g = i >> 7, c = i & 127;
        int ch = c >> 3, cc = c & 7;
        float s = g1[i] * rsqrtf(v1[i] + EPS);
        float t = be1[i] - m1[i] * s;
        float* base = ws + OFF_T1W + g*640 + ch*40;
        base[cc] = t / s;
        float* wd = base + 8 + cc*4;
        const float* wsrc = W1 + g*512 + c*4;
        wd[0] = s * wsrc[0];
        wd[1] = s * wsrc[1];
        wd[2] = s * wsrc[2];
        wd[3] = s * wsrc[3];
    }
    // W3 re-laid [kk][ci][g][f], pre-scaled by s3
    for (int i = gid; i < 4608; i += stride) {
        int f  = i & 3;
        int g  = (i >> 2) & 31;
        int ci = (i >> 7) & 3;
        int kk = i >> 9;               // 0..8
        int k = g*4 + f;
        float s3 = g3[k] * rsqrtf(v3[k] + EPS);
        ws[OFF_W3S + i] = W3[g*144 + kk*16 + ci*4 + f] * s3;
    }
    if (gid < 128) {
        float s2 = g2[gid] * rsqrtf(v2[gid] + EPS);
        ws[OFF_S2 + gid] = s2;
        ws[OFF_T2 + gid] = be2[gid] + (b1[gid] - m2[gid]) * s2;
        float s3 = g3[gid] * rsqrtf(v3[gid] + EPS);
        ws[OFF_T3 + gid] = be3[gid] + (b3[gid] - m3[gid]) * s3;
    } else if (gid >= 256 && gid < 512) {
        int co = gid - 256;
        float acc = 0.f;
        for (int g = 0; g < 32; ++g) acc += b2[g*256 + co];
        ws[OFF_BSUM + co] = acc;
    }
}

// Stage 1: grid = 392 px-tiles (128 px) x 2 group-halves; block 512 = 8 waves.
__global__ __launch_bounds__(512)
void stage1_kernel(const float* __restrict__ x,
                   const float* __restrict__ tabs,   // ws
                   float* __restrict__ uout) {       // ws + OFF_U
    __shared__ float4 xs4[4096];   // 64 KB: 128 px x 32 float4, swizzled
    int tid = threadIdx.x;
    int tile  = blockIdx.x >> 1;
    int ghalf = blockIdx.x & 1;

    const float4* xg = (const float4*)x + (size_t)tile * 4096;
    for (int i = tid; i < 4096; i += 512) {
        int p = i >> 5, c4 = i & 31;
        xs4[p*32 + (c4 ^ (p & 31))] = xg[i];
    }
    __syncthreads();

    int lane = tid & 63;
    int gbase = __builtin_amdgcn_readfirstlane(ghalf*16 + (tid >> 6)*2);
    int lsw = lane & 31;

    float accA[2][4], accB[2][4];
    #pragma unroll
    for (int gi = 0; gi < 2; ++gi)
        #pragma unroll
        for (int f = 0; f < 4; ++f) { accA[gi][f] = 0.f; accB[gi][f] = 0.f; }

    #pragma unroll 1
    for (int ch = 0; ch < 16; ++ch) {
        float xa[8], xb[8];
        *(float4*)&xa[0] = xs4[lane*32      + ((2*ch    ) ^ lsw)];
        *(float4*)&xa[4] = xs4[lane*32      + ((2*ch + 1) ^ lsw)];
        *(float4*)&xb[0] = xs4[(64+lane)*32 + ((2*ch    ) ^ lsw)];
        *(float4*)&xb[4] = xs4[(64+lane)*32 + ((2*ch + 1) ^ lsw)];
        #pragma unroll
        for (int gi = 0; gi < 2; ++gi) {
            const float* tb = tabs + OFF_T1W + (gbase + gi)*640 + ch*40;
            #pragma unroll
            for (int cc = 0; cc < 8; ++cc) {
                float tp = tb[cc];                          // SGPR
                float4 w = *(const float4*)(tb + 8 + cc*4); // SGPRs
                float za = fmaxf(xa[cc] + tp, 0.f);
                float zb = fmaxf(xb[cc] + tp, 0.f);
                accA[gi][0] = fmaf(za, w.x, accA[gi][0]);
                accA[gi][1] = fmaf(za, w.y, accA[gi][1]);
                accA[gi][2] = fmaf(za, w.z, accA[gi][2]);
                accA[gi][3] = fmaf(za, w.w, accA[gi][3]);
                accB[gi][0] = fmaf(zb, w.x, accB[gi][0]);
                accB[gi][1] = fmaf(zb, w.y, accB[gi][1]);
                accB[gi][2] = fmaf(zb, w.z, accB[gi][2]);
                accB[gi][3] = fmaf(zb, w.w, accB[gi][3]);
            }
        }
    }

    ushort4* U4 = (ushort4*)uout;
    size_t pxA = (size_t)tile * 128 + lane;
    #pragma unroll
    for (int gi = 0; gi < 2; ++gi) {
        int g = gbase + gi;
        float4 s2v = ((const float4*)(tabs + OFF_S2))[g];
        float4 t2v = ((const float4*)(tabs + OFF_T2))[g];
        ushort4 oa, ob;
        oa.x = f2bf(fmaxf(fmaf(accA[gi][0], s2v.x, t2v.x), 0.f));
        oa.y = f2bf(fmaxf(fmaf(accA[gi][1], s2v.y, t2v.y), 0.f));
        oa.z = f2bf(fmaxf(fmaf(accA[gi][2], s2v.z, t2v.z), 0.f));
        oa.w = f2bf(fmaxf(fmaf(accA[gi][3], s2v.w, t2v.w), 0.f));
        ob.x = f2bf(fmaxf(fmaf(accB[gi][0], s2v.x, t2v.x), 0.f));
        ob.y = f2bf(fmaxf(fmaf(accB[gi][1], s2v.y, t2v.y), 0.f));
        ob.z = f2bf(fmaxf(fmaf(accB[gi][2], s2v.z, t2v.z), 0.f));
        ob.w = f2bf(fmaxf(fmaf(accB[gi][3], s2v.w, t2v.w), 0.f));
        U4[(size_t)g * NPIX + pxA]      = oa;
        U4[(size_t)g * NPIX + pxA + 64] = ob;
    }
}

// Stage 2: block = one output row (b, oh): 28 opx, 512 threads, grid 448.
// U patch (3 rows x 56 px x 32 g) staged to LDS with coalesced 448B runs,
// XOR-swizzled so px-major writes and g-major reads are both bank-clean.
// Conv thread = (g, ow): each ushort4 feeds 16 FMAs (4ci x 4f), zero f-dup.
// Phase B: thread = (co, px-half), 14 opx accumulators.
__global__ __launch_bounds__(512)
void stage2_kernel(const float* __restrict__ x,
                   const float* __restrict__ W2,     // [128,256]
                   const float* __restrict__ tabs,   // ws
                   const float* __restrict__ U,      // ws + OFF_U (bf16)
                   float* __restrict__ out) {
    __shared__ ushort4 patch[3*58*32];   // [r][ics][g ^ (ics&31)]  44544 B
    __shared__ float w3t[4608];          // [kk][ci][g][f]          18432 B
    __shared__ float vs[28*128];         // [ow][k]                 14336 B
    __shared__ float t3s[128];
    __shared__ float res_s[28];

    int tid = threadIdx.x;
    int bo = blockIdx.x;                 // b*28 + oh
    int b = bo / 28, oh = bo - b*28;

    for (int i = tid; i < 4608; i += 512) w3t[i] = tabs[OFF_W3S + i];
    if (tid < 128) t3s[tid] = tabs[OFF_T3 + tid];
    // zero-fill pad column ics=0 (covers ic=-1; swizzle is identity there)
    if (tid >= 128 && tid < 224) {
        int j = tid - 128;
        int r = j >> 5, g = j & 31;
        patch[(r*58)*32 + g] = make_ushort4(0, 0, 0, 0);
    }

    // ---- stage U patch: rows ih = 2oh-1..2oh+1, ic 0..55, all 32 g ----
    {
        const ushort4* Uu = (const ushort4*)U;
        #pragma unroll 1
        for (int i = tid; i < 5376; i += 512) {
            int g = i / 168;
            int rem = i - g*168;
            int r = rem / 56;            // 0..2
            int ic = rem - r*56;         // 0..55
            int ih = 2*oh - 1 + r;
            ushort4 v = make_ushort4(0, 0, 0, 0);
            if (ih >= 0)
                v = Uu[(size_t)g * NPIX + (b*56 + ih)*56 + ic];
            int ics = ic + 1;
            patch[(r*58 + ics)*32 + (g ^ (ics & 31))] = v;
        }
    }

    // ---- residual: res[p] = sum_c x[b, 2oh, 2p, c] ----
    {
        int p = tid >> 4, l = tid & 15;
        if (p < 28) {
            const float* xp = x + (size_t)((b*56 + 2*oh)*56 + 2*p) * 128 + l;
            float rv = 0.f;
            #pragma unroll
            for (int c = 0; c < 8; ++c) rv += xp[c*16];
            #pragma unroll
            for (int off = 8; off; off >>= 1) rv += __shfl_down(rv, off, 16);
            if (l == 0) res_s[p] = rv;
        }
    }
    __syncthreads();

    // ---- 3x3 stride-2 conv from LDS: thread = (g, slot); ow = s, s+16 ----
    {
        int g = tid & 31, s = tid >> 5;  // s 0..15
        int ow0 = s, ow1 = s + 16;
        bool has1 = (ow1 < 28);
        float acc0[4] = {0.f, 0.f, 0.f, 0.f};
        float acc1[4] = {0.f, 0.f, 0.f, 0.f};
        #pragma unroll
        for (int kk = 0; kk < 9; ++kk) {
            int kh = kk / 3, kw = kk - kh*3;
            int ics0 = 2*ow0 + kw;                    // (2*ow-1+kw)+1, >= 0
            int ics1 = has1 ? (2*ow1 + kw) : 0;
            ushort4 ua = patch[(kh*58 + ics0)*32 + (g ^ (ics0 & 31))];
            ushort4 ub = patch[(kh*58 + ics1)*32 + (g ^ (ics1 & 31))];
            const float* wb = w3t + kk*512 + g*4;
            float4 w0 = *(const float4*)(wb);         // ci=0, f 0..3
            float4 w1 = *(const float4*)(wb + 128);
            float4 w2v = *(const float4*)(wb + 256);
            float4 w3v = *(const float4*)(wb + 384);
            float a0 = bf2f(ua.x), a1 = bf2f(ua.y), a2 = bf2f(ua.z), a3 = bf2f(ua.w);
            float b0 = bf2f(ub.x), b1v = bf2f(ub.y), b2v = bf2f(ub.z), b3v = bf2f(ub.w);
            acc0[0] = fmaf(a0, w0.x, acc0[0]); acc0[1] = fmaf(a0, w0.y, acc0[1]);
            acc0[2] = fmaf(a0, w0.z, acc0[2]); acc0[3] = fmaf(a0, w0.w, acc0[3]);
            acc0[0] = fmaf(a1, w1.x, acc0[0]); acc0[1] = fmaf(a1, w1.y, acc0[1]);
            acc0[2] = fmaf(a1, w1.z, acc0[2]); acc0[3] = fmaf(a1, w1.w, acc0[3]);
            acc0[0] = fmaf(a2, w2v.x, acc0[0]); acc0[1] = fmaf(a2, w2v.y, acc0[1]);
            acc0[2] = fmaf(a2, w2v.z, acc0[2]); acc0[3] = fmaf(a2, w2v.w, acc0[3]);
            acc0[0] = fmaf(a3, w3v.x, acc0[0]); acc0[1] = fmaf(a3, w3v.y, acc0[1]);
            acc0[2] = fmaf(a3, w3v.z, acc0[2]); acc0[3] = fmaf(a3, w3v.w, acc0[3]);
            acc1[0] = fmaf(b0, w0.x, acc1[0]); acc1[1] = fmaf(b0, w0.y, acc1[1]);
            acc1[2] = fmaf(b0, w0.z, acc1[2]); acc1[3] = fmaf(b0, w0.w, acc1[3]);
            acc1[0] = fmaf(b1v, w1.x, acc1[0]); acc1[1] = fmaf(b1v, w1.y, acc1[1]);
            acc1[2] = fmaf(b1v, w1.z, acc1[2]); acc1[3] = fmaf(b1v, w1.w, acc1[3]);
            acc1[0] = fmaf(b2v, w2v.x, acc1[0]); acc1[1] = fmaf(b2v, w2v.y, acc1[1]);
            acc1[2] = fmaf(b2v, w2v.z, acc1[2]); acc1[3] = fmaf(b2v, w2v.w, acc1[3]);
            acc1[0] = fmaf(b3v, w3v.x, acc1[0]); acc1[1] = fmaf(b3v, w3v.y, acc1[1]);
            acc1[2] = fmaf(b3v, w3v.z, acc1[2]); acc1[3] = fmaf(b3v, w3v.w, acc1[3]);
        }
        float4 t3v = *(const float4*)(t3s + g*4);
        float4 o0;
        o0.x = fmaxf(acc0[0] + t3v.x, 0.f);
        o0.y = fmaxf(acc0[1] + t3v.y, 0.f);
        o0.z = fmaxf(acc0[2] + t3v.z, 0.f);
        o0.w = fmaxf(acc0[3] + t3v.w, 0.f);
        *(float4*)&vs[ow0*128 + g*4] = o0;
        if (has1) {
            float4 o1;
            o1.x = fmaxf(acc1[0] + t3v.x, 0.f);
            o1.y = fmaxf(acc1[1] + t3v.y, 0.f);
            o1.z = fmaxf(acc1[2] + t3v.z, 0.f);
            o1.w = fmaxf(acc1[3] + t3v.w, 0.f);
            *(float4*)&vs[ow1*128 + g*4] = o1;
        }
    }
    __syncthreads();

    // ---- phase B: out[opx][co] = vs @ W2 + bsum + res ----
    {
        int co = tid & 255, h = tid >> 8;
        int p0 = h * 14;
        float acc[14];
        float bs = tabs[OFF_BSUM + co];
        #pragma unroll
        for (int p = 0; p < 14; ++p) acc[p] = bs;
        const float* W2c = W2 + co;
        #pragma unroll 4
        for (int k4 = 0; k4 < 32; ++k4) {
            float w0 = W2c[(4*k4+0)*256];
            float w1 = W2c[(4*k4+1)*256];
            float w2 = W2c[(4*k4+2)*256];
            float w3 = W2c[(4*k4+3)*256];
            #pragma unroll
            for (int p = 0; p < 14; ++p) {
                float4 v = *(const float4*)&vs[(p0 + p)*128 + k4*4];  // broadcast
                acc[p] = fmaf(v.x, w0, acc[p]);
                acc[p] = fmaf(v.y, w1, acc[p]);
                acc[p] = fmaf(v.z, w2, acc[p]);
                acc[p] = fmaf(v.w, w3, acc[p]);
            }
        }
        size_t obase = (size_t)bo * 28 * 256;    // opx_global = bo*28 + ow
        #pragma unroll
        for (int p = 0; p < 14; ++p)
            out[obase + (size_t)(p0 + p)*256 + co] = acc[p] + res_s[p0 + p];
    }
}

extern "C" void kernel_launch(void* const* d_in, const int* in_sizes, int n_in,
                              void* d_out, int out_size, void* d_ws, size_t ws_size,
                              hipStream_t stream) {
    const float* x   = (const float*)d_in[0];
    const float* g1  = (const float*)d_in[1];
    const float* be1 = (const float*)d_in[2];
    const float* m1  = (const float*)d_in[3];
    const float* v1  = (const float*)d_in[4];
    const float* W1  = (const float*)d_in[5];
    const float* b1  = (const float*)d_in[6];
    const float* g2  = (const float*)d_in[7];
    const float* be2 = (const float*)d_in[8];
    const float* m2  = (const float*)d_in[9];
    const float* v2  = (const float*)d_in[10];
    const float* W3  = (const float*)d_in[11];
    const float* b3  = (const float*)d_in[12];
    const float* g3  = (const float*)d_in[13];
    const float* be3 = (const float*)d_in[14];
    const float* m3  = (const float*)d_in[15];
    const float* v3  = (const float*)d_in[16];
    const float* W2  = (const float*)d_in[17];
    const float* b2  = (const float*)d_in[18];
    float* out = (float*)d_out;
    float* ws  = (float*)d_ws;

    prep_kernel<<<32, 256, 0, stream>>>(g1, be1, m1, v1, W1, b1, g2, be2, m2,
                                        v2, W3, b3, g3, be3, m3, v3, b2, ws);
    stage1_kernel<<<(NPIX / 128) * 2, 512, 0, stream>>>(x, ws, ws + OFF_U);
    stage2_kernel<<<16 * 28, 512, 0, stream>>>(x, W2, ws, ws + OFF_U, out);
}

// Round 2
// 178.286 us; speedup vs baseline: 1.0551x; 1.0551x over previous
//
#include <hip/hip_runtime.h>

#define EPS 1e-3f
#define NPIX  50176   // 16*56*56
#define NOPIX 12544   // 16*28*28

// ws float offsets
#define OFF_T1W  0        // [32 g][16 ch][8 t' + 32 w'] = 20480 (w' = s1*W1, t' = t1/s1)
#define OFF_S2   20480    // [32][4]
#define OFF_T2   20608    // [32][4]
#define OFF_T3   20736    // [128]
#define OFF_BSUM 20864    // [256]
#define OFF_W3S  21120    // [128 k][36 = 9kk x 4ci] pre-scaled by s3
#define OFF_U    25728    // [32 g][50176 px] ushort4 (bf16, g-planar)
#define OFF_V    3236992  // [12544 opx][128 k] f32 conv3 output (post BN3+ReLU)

__device__ __forceinline__ unsigned short f2bf(float f) {
    unsigned u = __float_as_uint(f);
    return (unsigned short)((u + 0x7fffu + ((u >> 16) & 1u)) >> 16);
}
__device__ __forceinline__ float bf2f(unsigned short s) {
    return __uint_as_float(((unsigned)s) << 16);
}

__global__ __launch_bounds__(256)
void prep_kernel(const float* __restrict__ g1, const float* __restrict__ be1,
                 const float* __restrict__ m1, const float* __restrict__ v1,
                 const float* __restrict__ W1, const float* __restrict__ b1,
                 const float* __restrict__ g2, const float* __restrict__ be2,
                 const float* __restrict__ m2, const float* __restrict__ v2,
                 const float* __restrict__ W3, const float* __restrict__ b3,
                 const float* __restrict__ g3, const float* __restrict__ be3,
                 const float* __restrict__ m3, const float* __restrict__ v3,
                 const float* __restrict__ b2, float* __restrict__ ws) {
    int gid = blockIdx.x * 256 + threadIdx.x;
    int stride = gridDim.x * 256;
    // T1W: per (g,c): t' = t1/s1 and w'_f = s1*W1[c][f]   (s1 > 0 always)
    for (int i = gid; i < 4096; i += stride) {
        int g = i >> 7, c = i & 127;
        int ch = c >> 3, cc = c & 7;
        float s = g1[i] * rsqrtf(v1[i] + EPS);
        float t = be1[i] - m1[i] * s;
        float* base = ws + OFF_T1W + g*640 + ch*40;
        base[cc] = t / s;
        float* wd = base + 8 + cc*4;
        const float* wsrc = W1 + g*512 + c*4;
        wd[0] = s * wsrc[0];
        wd[1] = s * wsrc[1];
        wd[2] = s * wsrc[2];
        wd[3] = s * wsrc[3];
    }
    // W3 re-laid [k][kk*4+ci], pre-scaled by s3  (k = g*4+f)
    for (int i = gid; i < 4608; i += stride) {
        int k = i / 36, j = i - k*36;
        int kk = j >> 2, ci = j & 3;
        int g = k >> 2, f = k & 3;
        float s3 = g3[k] * rsqrtf(v3[k] + EPS);
        ws[OFF_W3S + i] = W3[g*144 + kk*16 + ci*4 + f] * s3;
    }
    if (gid < 128) {
        float s2 = g2[gid] * rsqrtf(v2[gid] + EPS);
        ws[OFF_S2 + gid] = s2;
        ws[OFF_T2 + gid] = be2[gid] + (b1[gid] - m2[gid]) * s2;
        float s3 = g3[gid] * rsqrtf(v3[gid] + EPS);
        ws[OFF_T3 + gid] = be3[gid] + (b3[gid] - m3[gid]) * s3;
    } else if (gid >= 256 && gid < 512) {
        int co = gid - 256;
        float acc = 0.f;
        for (int g = 0; g < 32; ++g) acc += b2[g*256 + co];
        ws[OFF_BSUM + co] = acc;
    }
}

// Stage 1: grid = 392 px-tiles (128 px) x 2 group-halves; block 512 = 8 waves.
__global__ __launch_bounds__(512)
void stage1_kernel(const float* __restrict__ x,
                   const float* __restrict__ tabs,   // ws
                   float* __restrict__ uout) {       // ws + OFF_U
    __shared__ float4 xs4[4096];   // 64 KB: 128 px x 32 float4, swizzled
    int tid = threadIdx.x;
    int tile  = blockIdx.x >> 1;
    int ghalf = blockIdx.x & 1;

    const float4* xg = (const float4*)x + (size_t)tile * 4096;
    for (int i = tid; i < 4096; i += 512) {
        int p = i >> 5, c4 = i & 31;
        xs4[p*32 + (c4 ^ (p & 31))] = xg[i];
    }
    __syncthreads();

    int lane = tid & 63;
    int gbase = __builtin_amdgcn_readfirstlane(ghalf*16 + (tid >> 6)*2);
    int lsw = lane & 31;

    float accA[2][4], accB[2][4];
    #pragma unroll
    for (int gi = 0; gi < 2; ++gi)
        #pragma unroll
        for (int f = 0; f < 4; ++f) { accA[gi][f] = 0.f; accB[gi][f] = 0.f; }

    #pragma unroll 1
    for (int ch = 0; ch < 16; ++ch) {
        float xa[8], xb[8];
        *(float4*)&xa[0] = xs4[lane*32      + ((2*ch    ) ^ lsw)];
        *(float4*)&xa[4] = xs4[lane*32      + ((2*ch + 1) ^ lsw)];
        *(float4*)&xb[0] = xs4[(64+lane)*32 + ((2*ch    ) ^ lsw)];
        *(float4*)&xb[4] = xs4[(64+lane)*32 + ((2*ch + 1) ^ lsw)];
        #pragma unroll
        for (int gi = 0; gi < 2; ++gi) {
            const float* tb = tabs + OFF_T1W + (gbase + gi)*640 + ch*40;
            #pragma unroll
            for (int cc = 0; cc < 8; ++cc) {
                float tp = tb[cc];                          // SGPR
                float4 w = *(const float4*)(tb + 8 + cc*4); // SGPRs
                float za = fmaxf(xa[cc] + tp, 0.f);
                float zb = fmaxf(xb[cc] + tp, 0.f);
                accA[gi][0] = fmaf(za, w.x, accA[gi][0]);
                accA[gi][1] = fmaf(za, w.y, accA[gi][1]);
                accA[gi][2] = fmaf(za, w.z, accA[gi][2]);
                accA[gi][3] = fmaf(za, w.w, accA[gi][3]);
                accB[gi][0] = fmaf(zb, w.x, accB[gi][0]);
                accB[gi][1] = fmaf(zb, w.y, accB[gi][1]);
                accB[gi][2] = fmaf(zb, w.z, accB[gi][2]);
                accB[gi][3] = fmaf(zb, w.w, accB[gi][3]);
            }
        }
    }

    ushort4* U4 = (ushort4*)uout;
    size_t pxA = (size_t)tile * 128 + lane;
    #pragma unroll
    for (int gi = 0; gi < 2; ++gi) {
        int g = gbase + gi;
        float4 s2v = ((const float4*)(tabs + OFF_S2))[g];
        float4 t2v = ((const float4*)(tabs + OFF_T2))[g];
        ushort4 oa, ob;
        oa.x = f2bf(fmaxf(fmaf(accA[gi][0], s2v.x, t2v.x), 0.f));
        oa.y = f2bf(fmaxf(fmaf(accA[gi][1], s2v.y, t2v.y), 0.f));
        oa.z = f2bf(fmaxf(fmaf(accA[gi][2], s2v.z, t2v.z), 0.f));
        oa.w = f2bf(fmaxf(fmaf(accA[gi][3], s2v.w, t2v.w), 0.f));
        ob.x = f2bf(fmaxf(fmaf(accB[gi][0], s2v.x, t2v.x), 0.f));
        ob.y = f2bf(fmaxf(fmaf(accB[gi][1], s2v.y, t2v.y), 0.f));
        ob.z = f2bf(fmaxf(fmaf(accB[gi][2], s2v.z, t2v.z), 0.f));
        ob.w = f2bf(fmaxf(fmaf(accB[gi][3], s2v.w, t2v.w), 0.f));
        U4[(size_t)g * NPIX + pxA]      = oa;
        U4[(size_t)g * NPIX + pxA + 64] = ob;
    }
}

// Stage 2a: 3x3 stride-2 conv. Block = quarter-row (7 opx), 256 thr, grid 1792.
// LDS: only the U patch (3 rows x 16 cols x 32 g ushort4 = 12.3 KB) -> many
// blocks/CU. Thread = (k = g*4+f, parity s); its 36 weights live in VGPRs
// (9 float4 from L2-hot [k][36] table). Writes V[opx][128] f32 (post BN3+ReLU).
__global__ __launch_bounds__(256)
void stage2a_kernel(const float* __restrict__ tabs,   // ws
                    const float* __restrict__ U,      // ws + OFF_U (bf16)
                    float* __restrict__ V) {          // ws + OFF_V
    __shared__ ushort4 patch[3*16*32];   // [r][c][g ^ c]   12288 B

    int tid = threadIdx.x;
    int row = blockIdx.x >> 2;           // b*28 + oh
    int q   = blockIdx.x & 3;            // quarter: opx = q*7 .. q*7+6
    int b = row / 28, oh = row - b*28;

    // ---- stage U patch: rows ih = 2oh-1..2oh+1, cols ic = 14q-1 .. 14q+13 ----
    {
        const ushort4* Uu = (const ushort4*)U;
        #pragma unroll 1
        for (int i = tid; i < 1440; i += 256) {
            int g = i / 45;
            int rem = i - g*45;
            int r = rem / 15;            // 0..2
            int c = rem - r*15;          // 0..14
            int ih = 2*oh - 1 + r;
            int ic = 14*q - 1 + c;
            ushort4 v = make_ushort4(0, 0, 0, 0);
            if (ih >= 0 && ic >= 0)
                v = Uu[(size_t)g * NPIX + (b*56 + ih)*56 + ic];
            patch[(r*16 + c)*32 + (g ^ c)] = v;
        }
    }

    // weights into VGPRs: 9 float4 per thread (L2-hot table)
    int k = tid & 127, s = tid >> 7;     // s in {0,1}
    int g = k >> 2;
    float4 w[9];
    {
        const float4* wk = (const float4*)(tabs + OFF_W3S + k*36);
        #pragma unroll
        for (int kk = 0; kk < 9; ++kk) w[kk] = wk[kk];
    }
    float t3 = tabs[OFF_T3 + k];
    __syncthreads();

    // ---- conv: opx_l = s + 2j (parity split), each ushort4 read broadcast x4 f ----
    #pragma unroll
    for (int j = 0; j < 4; ++j) {
        int opx_l = s + 2*j;
        if (opx_l > 6) break;
        float acc = 0.f;
        #pragma unroll
        for (int kh = 0; kh < 3; ++kh) {
            #pragma unroll
            for (int kw = 0; kw < 3; ++kw) {
                int cc = 2*opx_l + kw;   // 0..14
                ushort4 u = patch[(kh*16 + cc)*32 + (g ^ cc)];
                float4 wv = w[kh*3 + kw];
                acc = fmaf(bf2f(u.x), wv.x, acc);
                acc = fmaf(bf2f(u.y), wv.y, acc);
                acc = fmaf(bf2f(u.z), wv.z, acc);
                acc = fmaf(bf2f(u.w), wv.w, acc);
            }
        }
        int opx = row*28 + q*7 + opx_l;
        V[(size_t)opx*128 + k] = fmaxf(acc + t3, 0.f);
    }
}

// Stage 2b: 1x1 conv (GEMM) + bsum + residual. Block = 8 opx, 256 thr, grid 1568.
__global__ __launch_bounds__(256)
void stage2b_kernel(const float* __restrict__ x,
                    const float* __restrict__ W2,     // [128,256]
                    const float* __restrict__ tabs,   // ws
                    const float* __restrict__ V,      // ws + OFF_V
                    float* __restrict__ out) {
    __shared__ float vs[8*128];
    __shared__ float res_s[8];
    int tid = threadIdx.x;
    int opxBase = blockIdx.x * 8;

    // stage V rows (coalesced)
    {
        const float* Vb = V + (size_t)opxBase * 128;
        #pragma unroll
        for (int jj = 0; jj < 4; ++jj) vs[tid + 256*jj] = Vb[tid + 256*jj];
    }
    // residual: res[p] = sum_c x[b, 2oh, 2ow, c]
    {
        int p = tid >> 5, l = tid & 31;
        int opx = opxBase + p;
        int b = opx / 784, r = opx - b*784;
        int oh = r / 28, ow = r - oh*28;
        const float* xp = x + (size_t)((b*56 + 2*oh)*56 + 2*ow) * 128;
        float rv = xp[l] + xp[l+32] + xp[l+64] + xp[l+96];
        #pragma unroll
        for (int off = 16; off; off >>= 1) rv += __shfl_down(rv, off, 32);
        if (l == 0) res_s[p] = rv;
    }
    __syncthreads();

    // out[opx][co] = vs @ W2 + bsum + res, thread = co
    int co = tid;
    float acc[8];
    {
        float bs = tabs[OFF_BSUM + co];
        #pragma unroll
        for (int p = 0; p < 8; ++p) acc[p] = bs;
    }
    const float* W2c = W2 + co;
    #pragma unroll 4
    for (int k4 = 0; k4 < 32; ++k4) {
        float w0 = W2c[(4*k4+0)*256];
        float w1 = W2c[(4*k4+1)*256];
        float w2 = W2c[(4*k4+2)*256];
        float w3 = W2c[(4*k4+3)*256];
        #pragma unroll
        for (int p = 0; p < 8; ++p) {
            float4 v = *(const float4*)&vs[p*128 + k4*4];   // broadcast
            acc[p] = fmaf(v.x, w0, acc[p]);
            acc[p] = fmaf(v.y, w1, acc[p]);
            acc[p] = fmaf(v.z, w2, acc[p]);
            acc[p] = fmaf(v.w, w3, acc[p]);
        }
    }
    #pragma unroll
    for (int p = 0; p < 8; ++p)
        out[(size_t)(opxBase + p)*256 + co] = acc[p] + res_s[p];
}

extern "C" void kernel_launch(void* const* d_in, const int* in_sizes, int n_in,
                              void* d_out, int out_size, void* d_ws, size_t ws_size,
                              hipStream_t stream) {
    const float* x   = (const float*)d_in[0];
    const float* g1  = (const float*)d_in[1];
    const float* be1 = (const float*)d_in[2];
    const float* m1  = (const float*)d_in[3];
    const float* v1  = (const float*)d_in[4];
    const float* W1  = (const float*)d_in[5];
    const float* b1  = (const float*)d_in[6];
    const float* g2  = (const float*)d_in[7];
    const float* be2 = (const float*)d_in[8];
    const float* m2  = (const float*)d_in[9];
    const float* v2  = (const float*)d_in[10];
    const float* W3  = (const float*)d_in[11];
    const float* b3  = (const float*)d_in[12];
    const float* g3  = (const float*)d_in[13];
    const float* be3 = (const float*)d_in[14];
    const float* m3  = (const float*)d_in[15];
    const float* v3  = (const float*)d_in[16];
    const float* W2  = (const float*)d_in[17];
    const float* b2  = (const float*)d_in[18];
    float* out = (float*)d_out;
    float* ws  = (float*)d_ws;

    prep_kernel<<<32, 256, 0, stream>>>(g1, be1, m1, v1, W1, b1, g2, be2, m2,
                                        v2, W3, b3, g3, be3, m3, v3, b2, ws);
    stage1_kernel<<<(NPIX / 128) * 2, 512, 0, stream>>>(x, ws, ws + OFF_U);
    stage2a_kernel<<<448 * 4, 256, 0, stream>>>(ws, ws + OFF_U, ws + OFF_V);
    stage2b_kernel<<<NOPIX / 8, 256, 0, stream>>>(x, W2, ws, ws + OFF_V, out);
}